// Round 5
// baseline (77593.878 us; speedup 1.0000x reference)
//
#include <hip/hip_runtime.h>

// VanillaRNNLayer: B=32, T=2048, I=512, H=512 — ALL FP32.
//   phase 1: xp = x @ Wx^T + bx + bh   -> fp32 into d_out (consumed in place)
//   phase 2: h_t = tanh(xp_t + Wh h_{t-1}), 8 blocks/chain, Wh in VGPRs.
// R4 lesson: h-broadcast LDS reads at 64B stride = 4x bank overhead (1e8
// conflict cycles); serial 32-wide reduce on 2 waves; 4 barriers + s_sleep.
// This round: interleave-4 columns (bank floor), distributed reduce,
// 3 barriers/step, spin-poll, 8 parts on 256 CUs.

constexpr int Bb = 32, Tt = 2048, Ii = 512, Hh = 512;
constexpr int NP = 8;            // parts per chain
constexpr int RP = Hh / NP;      // 64 rows per part

static __device__ __forceinline__ float fast_tanh(float x) {
    float ax = fabsf(x);
    float e = __expf(-2.0f * ax);            // in (0,1], no overflow
    float r = (1.0f - e) / (1.0f + e);
    return copysignf(r, x);
}

// ---------------- Phase 1: xp GEMM, 128x128 tile, 8x8/thread ----------------
__global__ __launch_bounds__(256, 2)
void xproj_gemm(const float* __restrict__ x, const float* __restrict__ Wx,
                const float* __restrict__ bx, const float* __restrict__ bh,
                float* __restrict__ xp)
{
    constexpr int BM = 128, BK = 16, LDT = BM + 4;   // [k][m] transposed tiles
    __shared__ float As[BK][LDT];
    __shared__ float Bs[BK][LDT];

    const int tid = threadIdx.x;
    const int m0 = blockIdx.x * BM;          // 512 m-tiles
    const int n0 = blockIdx.y * BM;          // 4 n-tiles
    const int lrow = tid >> 1;               // 0..127
    const int lkh  = (tid & 1) * 8;          // 0 or 8
    const int tx = tid & 15, ty = tid >> 4;

    float acc[2][2][4][4] = {};              // [rowhalf][colhalf][i][j]

    for (int k0 = 0; k0 < Ii; k0 += BK) {
        float4 a0 = *reinterpret_cast<const float4*>(&x[(size_t)(m0 + lrow) * Ii + k0 + lkh]);
        float4 a1 = *reinterpret_cast<const float4*>(&x[(size_t)(m0 + lrow) * Ii + k0 + lkh + 4]);
        float4 b0 = *reinterpret_cast<const float4*>(&Wx[(size_t)(n0 + lrow) * Ii + k0 + lkh]);
        float4 b1 = *reinterpret_cast<const float4*>(&Wx[(size_t)(n0 + lrow) * Ii + k0 + lkh + 4]);
        __syncthreads();                     // prior compute done before overwrite
        As[lkh + 0][lrow] = a0.x; As[lkh + 1][lrow] = a0.y;
        As[lkh + 2][lrow] = a0.z; As[lkh + 3][lrow] = a0.w;
        As[lkh + 4][lrow] = a1.x; As[lkh + 5][lrow] = a1.y;
        As[lkh + 6][lrow] = a1.z; As[lkh + 7][lrow] = a1.w;
        Bs[lkh + 0][lrow] = b0.x; Bs[lkh + 1][lrow] = b0.y;
        Bs[lkh + 2][lrow] = b0.z; Bs[lkh + 3][lrow] = b0.w;
        Bs[lkh + 4][lrow] = b1.x; Bs[lkh + 5][lrow] = b1.y;
        Bs[lkh + 6][lrow] = b1.z; Bs[lkh + 7][lrow] = b1.w;
        __syncthreads();
        #pragma unroll
        for (int k = 0; k < BK; ++k) {
            float4 av[2], bv[2];
            av[0] = *reinterpret_cast<const float4*>(&As[k][ty * 4]);
            av[1] = *reinterpret_cast<const float4*>(&As[k][64 + ty * 4]);
            bv[0] = *reinterpret_cast<const float4*>(&Bs[k][tx * 4]);
            bv[1] = *reinterpret_cast<const float4*>(&Bs[k][64 + tx * 4]);
            #pragma unroll
            for (int rh = 0; rh < 2; ++rh) {
                const float* ap = reinterpret_cast<const float*>(&av[rh]);
                #pragma unroll
                for (int ch = 0; ch < 2; ++ch) {
                    const float* bp = reinterpret_cast<const float*>(&bv[ch]);
                    #pragma unroll
                    for (int i = 0; i < 4; ++i)
                        #pragma unroll
                        for (int j = 0; j < 4; ++j)
                            acc[rh][ch][i][j] += ap[i] * bp[j];
                }
            }
        }
    }

    float4 bias[2];
    #pragma unroll
    for (int ch = 0; ch < 2; ++ch) {
        int cb = n0 + ch * 64 + tx * 4;
        bias[ch] = make_float4(bx[cb] + bh[cb], bx[cb + 1] + bh[cb + 1],
                               bx[cb + 2] + bh[cb + 2], bx[cb + 3] + bh[cb + 3]);
    }
    #pragma unroll
    for (int rh = 0; rh < 2; ++rh)
        #pragma unroll
        for (int i = 0; i < 4; ++i) {
            size_t row = (size_t)(m0 + rh * 64 + ty * 4 + i);
            #pragma unroll
            for (int ch = 0; ch < 2; ++ch) {
                const float* bp = reinterpret_cast<const float*>(&bias[ch]);
                float4 v = make_float4(acc[rh][ch][i][0] + bp[0], acc[rh][ch][i][1] + bp[1],
                                       acc[rh][ch][i][2] + bp[2], acc[rh][ch][i][3] + bp[3]);
                *reinterpret_cast<float4*>(&xp[row * Hh + n0 + ch * 64 + tx * 4]) = v;
            }
        }
}

// ---------------- zero sync flags (tags are monotonic within a launch) -------
__global__ void zero_flags(unsigned int* __restrict__ flags)
{
    flags[threadIdx.x] = 0u;      // 512 u32 = 32 chains x 8 parts x 2 slots
}

// ---------------- Phase 2: scan, 8 blocks/chain, Wh slice in VGPRs ----------
// bid: chain c = bid&31, part P = bid>>5. All 8 parts of chain c land on
// XCD c%8 under round-robin (perf only). Thread (w=tid>>6, lane):
// rows P*64 + w*8 + (lane>>5)*4 + s (s=0..3); cols q*128 + (lane&31)*4 + i.
__global__ __launch_bounds__(512, 1)
void rnn_scan_mb(const float* __restrict__ Wh, const float* __restrict__ h0,
                 float* __restrict__ out, unsigned int* __restrict__ flags,
                 float* __restrict__ xbuf)
{
    const int bid = blockIdx.x;
    const int c = bid & 31;
    const int P = bid >> 5;
    const int tid = threadIdx.x;
    const int w = tid >> 6;          // wave 0..7
    const int lane = tid & 63;
    const int lp = lane & 31, hf = lane >> 5;
    const int lrow0 = w * 8 + hf * 4;          // local row base 0..60

    __shared__ __align__(16) float hs[Hh];
    __shared__ __align__(16) float pacc[RP][36];   // [row][lp]; pad: b128 stage1 = 8/bank floor
    __shared__ float red[NP][68];                  // [group][row]; conflict-free

    // ---- weights -> registers (16 float4 = 64 VGPR), pinned vs remat
    float4 wreg[4][4];
    #pragma unroll
    for (int s = 0; s < 4; ++s)
        #pragma unroll
        for (int q = 0; q < 4; ++q) {
            wreg[s][q] = *reinterpret_cast<const float4*>(
                &Wh[(size_t)(P * RP + lrow0 + s) * Hh + q * 128 + lp * 4]);
            asm volatile("" : "+v"(wreg[s][q].x), "+v"(wreg[s][q].y),
                              "+v"(wreg[s][q].z), "+v"(wreg[s][q].w));
        }

    hs[tid] = h0[(size_t)c * Hh + tid];

    float* ob = out + (size_t)c * Tt * Hh;           // xp rows -> h rows in place
    unsigned int* flg = flags + c * (NP * 2);        // [part*2 + slot]
    float* xb = xbuf + c * (Hh * 2);                 // [slot*512 + idx]

    float xp_cur = 0.f;
    if (tid < RP) xp_cur = ob[P * RP + tid];         // wave 0: xp row t=0
    __syncthreads();

    for (int t = 0; t < Tt; ++t) {
        // ---- FMA phase: 4 rows x 16 interleaved cols per thread
        float4 hv[4];
        #pragma unroll
        for (int q = 0; q < 4; ++q)
            hv[q] = *reinterpret_cast<const float4*>(&hs[q * 128 + lp * 4]);  // 4/bank floor
        #pragma unroll
        for (int s = 0; s < 4; ++s) {
            float sum = 0.f;
            #pragma unroll
            for (int q = 0; q < 4; ++q) {
                const float* wq = reinterpret_cast<const float*>(&wreg[s][q]);
                const float* hq = reinterpret_cast<const float*>(&hv[q]);
                sum += wq[0] * hq[0]; sum += wq[1] * hq[1];
                sum += wq[2] * hq[2]; sum += wq[3] * hq[3];
            }
            pacc[lrow0 + s][lp] = sum;               // b32, 2-way (free)
        }
        __syncthreads();                             // B1: pacc ready, hs reads done

        // ---- stage1: wave w reduces lp-group w for all 64 rows
        {
            float4 p4 = *reinterpret_cast<const float4*>(&pacc[lane][w * 4]);
            red[w][lane] = (p4.x + p4.y) + (p4.z + p4.w);
        }
        __syncthreads();                             // B2: red ready

        const int d = t & 1;
        if (w == 0) {                                // ---- stage2: wave 0 only
            float ssum = xp_cur;
            #pragma unroll
            for (int g = 0; g < NP; ++g) ssum += red[g][lane];   // conflict-free b32
            float hval = fast_tanh(ssum);
            ob[(size_t)t * Hh + P * RP + lane] = hval;
            if (t + 1 < Tt) {
                hs[P * RP + lane] = hval;
                __hip_atomic_store(&xb[d * Hh + P * RP + lane], hval,
                                   __ATOMIC_RELAXED, __HIP_MEMORY_SCOPE_AGENT);
                xp_cur = ob[(size_t)(t + 1) * Hh + P * RP + lane];  // prefetch next xp
                if (lane == 0)
                    __hip_atomic_store(&flg[P * 2 + d], (unsigned)(t + 1),
                                       __ATOMIC_RELEASE, __HIP_MEMORY_SCOPE_AGENT);
            } else {
                out[(size_t)Bb * Tt * Hh + (size_t)c * Hh + P * RP + lane] = hval;
            }
        }
        if (t + 1 >= Tt) break;

        // ---- fetch: wave w pulls remote part w (wave P's slice written locally)
        if (w != P) {
            if (lane == 0) {
                while (__hip_atomic_load(&flg[w * 2 + d], __ATOMIC_ACQUIRE,
                                         __HIP_MEMORY_SCOPE_AGENT) < (unsigned)(t + 1)) {}
            }
            hs[w * RP + lane] = __hip_atomic_load(&xb[d * Hh + w * RP + lane],
                                                  __ATOMIC_RELAXED, __HIP_MEMORY_SCOPE_AGENT);
        }
        __syncthreads();                             // B3: hs complete for next step
    }
}

// ---------------- Fallback single-block scan (tiny ws) ----------------
__global__ __launch_bounds__(512)
void rnn_scan_sb(const float* __restrict__ W, const float* __restrict__ h0,
                 float* __restrict__ out)
{
    const int b = blockIdx.x;
    const int j = threadIdx.x;
    __shared__ float hsb[2][Hh];
    hsb[0][j] = h0[(size_t)b * Hh + j];
    __syncthreads();

    float* ob = out + (size_t)b * Tt * Hh;
    const float* wbase = W + (size_t)j * Hh;

    float xp_cur = ob[j];
    int cur = 0;
    for (int t = 0; t < Tt; ++t) {
        float xp_next = (t + 1 < Tt) ? ob[(size_t)(t + 1) * Hh + j] : 0.0f;
        float4 a = make_float4(xp_cur, 0.0f, 0.0f, 0.0f);
        const float* h = hsb[cur];
        #pragma unroll 8
        for (int c4 = 0; c4 < Hh / 4; ++c4) {
            float4 wv = *reinterpret_cast<const float4*>(&wbase[c4 * 4]);
            float4 hv = *reinterpret_cast<const float4*>(&h[c4 * 4]);
            a.x += wv.x * hv.x; a.y += wv.y * hv.y;
            a.z += wv.z * hv.z; a.w += wv.w * hv.w;
        }
        float hn = tanhf((a.x + a.y) + (a.z + a.w));
        hsb[cur ^ 1][j] = hn;
        ob[(size_t)t * Hh + j] = hn;
        xp_cur = xp_next;
        cur ^= 1;
        __syncthreads();
    }
    out[(size_t)Bb * Tt * Hh + (size_t)b * Hh + j] = hsb[cur][j];
}

extern "C" void kernel_launch(void* const* d_in, const int* in_sizes, int n_in,
                              void* d_out, int out_size, void* d_ws, size_t ws_size,
                              hipStream_t stream)
{
    const float* x  = (const float*)d_in[0];
    const float* h0 = (const float*)d_in[1];
    const float* Wx = (const float*)d_in[2];
    const float* bx = (const float*)d_in[3];
    const float* Wh = (const float*)d_in[4];
    const float* bh = (const float*)d_in[5];
    float* out = (float*)d_out;

    dim3 g1(Bb * Tt / 128, Hh / 128);     // (512, 4)
    xproj_gemm<<<g1, 256, 0, stream>>>(x, Wx, bx, bh, out);

    const size_t flg_bytes = 512 * sizeof(unsigned int);           // 2 KB
    const size_t xb_bytes  = (size_t)Bb * Hh * 2 * sizeof(float);  // 128 KB
    if (ws_size >= flg_bytes + xb_bytes) {
        unsigned int* flags = (unsigned int*)d_ws;
        float* xbuf = (float*)((char*)d_ws + flg_bytes);
        zero_flags<<<1, 512, 0, stream>>>(flags);
        void* args[] = {(void*)&Wh, (void*)&h0, (void*)&out, (void*)&flags, (void*)&xbuf};
        hipLaunchCooperativeKernel((void*)rnn_scan_mb, dim3(NP * Bb), dim3(512),
                                   args, 0, stream);
    } else {
        rnn_scan_sb<<<Bb, Hh, 0, stream>>>(Wh, h0, out);
    }
}

// Round 6
// 4768.269 us; speedup vs baseline: 16.2730x; 16.2730x over previous
//
#include <hip/hip_runtime.h>

// VanillaRNNLayer: B=32, T=2048, I=512, H=512 — ALL FP32.
//   phase 1: xp = x @ Wx^T + bx + bh   -> fp32 into d_out (consumed in place)
//   phase 2: h_t = tanh(xp_t + Wh h_{t-1}), 8 blocks/chain, Wh slice in VGPRs.
// R5 lessons: (a) compiler REMATERIALIZES const-__restrict__ weight loads
// (VGPR=48) -> force residency with inline-asm loads; (b) acquire/release
// agent atomics emit per-iteration cache maintenance on multi-XCD -> storm.
// Use R4-proven recipe: RELAXED atomics + s_waitcnt vmcnt(0) + s_sleep polls.

constexpr int Bb = 32, Tt = 2048, Ii = 512, Hh = 512;
constexpr int NP = 8;            // parts (blocks) per chain
constexpr int RP = Hh / NP;      // 64 rows per part

static __device__ __forceinline__ float fast_tanh(float x) {
    float ax = fabsf(x);
    float e = __expf(-2.0f * ax);            // in (0,1], no overflow
    float r = (1.0f - e) / (1.0f + e);
    return copysignf(r, x);
}

// ---------------- Phase 1: xp GEMM, 128x128 tile, 8x8/thread ----------------
__global__ __launch_bounds__(256, 2)
void xproj_gemm(const float* __restrict__ x, const float* __restrict__ Wx,
                const float* __restrict__ bx, const float* __restrict__ bh,
                float* __restrict__ xp)
{
    constexpr int BM = 128, BK = 16, LDT = BM + 4;   // [k][m] transposed tiles
    __shared__ float As[BK][LDT];
    __shared__ float Bs[BK][LDT];

    const int tid = threadIdx.x;
    const int m0 = blockIdx.x * BM;
    const int n0 = blockIdx.y * BM;
    const int lrow = tid >> 1;               // 0..127
    const int lkh  = (tid & 1) * 8;          // 0 or 8
    const int tx = tid & 15, ty = tid >> 4;

    float acc[2][2][4][4] = {};

    for (int k0 = 0; k0 < Ii; k0 += BK) {
        float4 a0 = *reinterpret_cast<const float4*>(&x[(size_t)(m0 + lrow) * Ii + k0 + lkh]);
        float4 a1 = *reinterpret_cast<const float4*>(&x[(size_t)(m0 + lrow) * Ii + k0 + lkh + 4]);
        float4 b0 = *reinterpret_cast<const float4*>(&Wx[(size_t)(n0 + lrow) * Ii + k0 + lkh]);
        float4 b1 = *reinterpret_cast<const float4*>(&Wx[(size_t)(n0 + lrow) * Ii + k0 + lkh + 4]);
        __syncthreads();
        As[lkh + 0][lrow] = a0.x; As[lkh + 1][lrow] = a0.y;
        As[lkh + 2][lrow] = a0.z; As[lkh + 3][lrow] = a0.w;
        As[lkh + 4][lrow] = a1.x; As[lkh + 5][lrow] = a1.y;
        As[lkh + 6][lrow] = a1.z; As[lkh + 7][lrow] = a1.w;
        Bs[lkh + 0][lrow] = b0.x; Bs[lkh + 1][lrow] = b0.y;
        Bs[lkh + 2][lrow] = b0.z; Bs[lkh + 3][lrow] = b0.w;
        Bs[lkh + 4][lrow] = b1.x; Bs[lkh + 5][lrow] = b1.y;
        Bs[lkh + 6][lrow] = b1.z; Bs[lkh + 7][lrow] = b1.w;
        __syncthreads();
        #pragma unroll
        for (int k = 0; k < BK; ++k) {
            float4 av[2], bv[2];
            av[0] = *reinterpret_cast<const float4*>(&As[k][ty * 4]);
            av[1] = *reinterpret_cast<const float4*>(&As[k][64 + ty * 4]);
            bv[0] = *reinterpret_cast<const float4*>(&Bs[k][tx * 4]);
            bv[1] = *reinterpret_cast<const float4*>(&Bs[k][64 + tx * 4]);
            #pragma unroll
            for (int rh = 0; rh < 2; ++rh) {
                const float* ap = reinterpret_cast<const float*>(&av[rh]);
                #pragma unroll
                for (int ch = 0; ch < 2; ++ch) {
                    const float* bp = reinterpret_cast<const float*>(&bv[ch]);
                    #pragma unroll
                    for (int i = 0; i < 4; ++i)
                        #pragma unroll
                        for (int j = 0; j < 4; ++j)
                            acc[rh][ch][i][j] += ap[i] * bp[j];
                }
            }
        }
    }

    float4 bias[2];
    #pragma unroll
    for (int ch = 0; ch < 2; ++ch) {
        int cb = n0 + ch * 64 + tx * 4;
        bias[ch] = make_float4(bx[cb] + bh[cb], bx[cb + 1] + bh[cb + 1],
                               bx[cb + 2] + bh[cb + 2], bx[cb + 3] + bh[cb + 3]);
    }
    #pragma unroll
    for (int rh = 0; rh < 2; ++rh)
        #pragma unroll
        for (int i = 0; i < 4; ++i) {
            size_t row = (size_t)(m0 + rh * 64 + ty * 4 + i);
            #pragma unroll
            for (int ch = 0; ch < 2; ++ch) {
                const float* bp = reinterpret_cast<const float*>(&bias[ch]);
                float4 v = make_float4(acc[rh][ch][i][0] + bp[0], acc[rh][ch][i][1] + bp[1],
                                       acc[rh][ch][i][2] + bp[2], acc[rh][ch][i][3] + bp[3]);
                *reinterpret_cast<float4*>(&xp[row * Hh + n0 + ch * 64 + tx * 4]) = v;
            }
        }
}

// ---------------- zero sync flags (tags monotonic within a launch) ----------
__global__ void zero_flags(unsigned int* __restrict__ flags)
{
    flags[threadIdx.x] = 0u;      // 512 = 32 chains x 8 parts x 2 slots
}

// ---------------- Phase 2: scan, 8 blocks/chain, Wh slice pinned in VGPRs ---
// bid: chain c = bid&31, part P = bid>>5. Thread (w=tid>>6, lane):
// rows P*64 + w*8 + (lane>>5)*4 + s (s=0..3); cols q*128 + (lane&31)*4 + i.
// Wave P does stage2+publish (it never fetches); waves w!=P fetch part w.
__global__ __launch_bounds__(512, 2)
void rnn_scan_mb(const float* __restrict__ Wh, const float* __restrict__ h0,
                 float* __restrict__ out, unsigned int* __restrict__ flags,
                 float* __restrict__ xbuf)
{
    const int bid = blockIdx.x;
    const int c = bid & 31;
    const int P = bid >> 5;
    const int tid = threadIdx.x;
    const int w = tid >> 6;          // wave 0..7
    const int lane = tid & 63;
    const int lp = lane & 31, hf = lane >> 5;
    const int lrow0 = w * 8 + hf * 4;          // local row base 0..60

    __shared__ __align__(16) float hs[Hh];
    __shared__ __align__(16) float pacc[RP][36];   // [row][lp]
    __shared__ float red[NP][68];                  // [lp-group][row]

    // ---- weights -> VGPRs via opaque asm loads (compiler cannot remat) ----
    float4 wreg[4][4];
    #pragma unroll
    for (int s = 0; s < 4; ++s)
        #pragma unroll
        for (int q = 0; q < 4; ++q) {
            const float* ap = &Wh[(size_t)(P * RP + lrow0 + s) * Hh + q * 128 + lp * 4];
            asm volatile("global_load_dwordx4 %0, %1, off"
                         : "=v"(wreg[s][q]) : "v"(ap));
        }
    asm volatile("s_waitcnt vmcnt(0)" ::: "memory");

    hs[tid] = h0[(size_t)c * Hh + tid];

    float* ob = out + (size_t)c * Tt * Hh;           // xp rows -> h rows in place
    unsigned int* flg = flags + c * (NP * 2);        // [part*2 + slot]
    float* xb = xbuf + c * (Hh * 2);                 // [slot*512 + idx]

    float xp_cur = 0.f;
    if (w == P) xp_cur = ob[P * RP + lane];          // wave P holds xp row t=0
    __syncthreads();

    for (int t = 0; t < Tt; ++t) {
        // ---- FMA phase: 4 rows x 16 interleaved cols per thread
        float4 hv[4];
        #pragma unroll
        for (int q = 0; q < 4; ++q)
            hv[q] = *reinterpret_cast<const float4*>(&hs[q * 128 + lp * 4]);
        #pragma unroll
        for (int s = 0; s < 4; ++s) {
            float sum = 0.f;
            #pragma unroll
            for (int q = 0; q < 4; ++q) {
                const float* wq = reinterpret_cast<const float*>(&wreg[s][q]);
                const float* hq = reinterpret_cast<const float*>(&hv[q]);
                sum += wq[0] * hq[0]; sum += wq[1] * hq[1];
                sum += wq[2] * hq[2]; sum += wq[3] * hq[3];
            }
            pacc[lrow0 + s][lp] = sum;
        }
        __syncthreads();                             // B1: pacc ready, hs reads done

        // ---- stage1: wave w reduces lp-group w (4 partials) for all 64 rows
        {
            float4 p4 = *reinterpret_cast<const float4*>(&pacc[lane][w * 4]);
            red[w][lane] = (p4.x + p4.y) + (p4.z + p4.w);
        }
        __syncthreads();                             // B2: red ready

        const int d = t & 1;
        if (w == P) {                                // ---- stage2 + publish
            float ssum = xp_cur;
            #pragma unroll
            for (int g = 0; g < NP; ++g) ssum += red[g][lane];
            float hval = fast_tanh(ssum);
            ob[(size_t)t * Hh + P * RP + lane] = hval;
            hs[P * RP + lane] = hval;
            if (t + 1 < Tt) {
                __hip_atomic_store(&xb[d * Hh + P * RP + lane], hval,
                                   __ATOMIC_RELAXED, __HIP_MEMORY_SCOPE_AGENT);
                asm volatile("s_waitcnt vmcnt(0)" ::: "memory");   // stores ack'd at IC
                if (lane == 0)
                    __hip_atomic_store(&flg[P * 2 + d], (unsigned)(t + 1),
                                       __ATOMIC_RELAXED, __HIP_MEMORY_SCOPE_AGENT);
                xp_cur = ob[(size_t)(t + 1) * Hh + P * RP + lane];  // prefetch next xp
            } else {
                out[(size_t)Bb * Tt * Hh + (size_t)c * Hh + P * RP + lane] = hval;
            }
        }
        if (t + 1 >= Tt) break;

        // ---- fetch: wave w pulls remote part w
        if (w != P) {
            if (lane == 0) {
                while (__hip_atomic_load(&flg[w * 2 + d], __ATOMIC_RELAXED,
                                         __HIP_MEMORY_SCOPE_AGENT) < (unsigned)(t + 1)) {
                    __builtin_amdgcn_s_sleep(1);
                }
            }
            hs[w * RP + lane] = __hip_atomic_load(&xb[d * Hh + w * RP + lane],
                                                  __ATOMIC_RELAXED, __HIP_MEMORY_SCOPE_AGENT);
        }
        __syncthreads();                             // B3: hs complete for next step
    }
}

// ---------------- Fallback single-block scan (tiny ws) ----------------
__global__ __launch_bounds__(512)
void rnn_scan_sb(const float* __restrict__ W, const float* __restrict__ h0,
                 float* __restrict__ out)
{
    const int b = blockIdx.x;
    const int j = threadIdx.x;
    __shared__ float hsb[2][Hh];
    hsb[0][j] = h0[(size_t)b * Hh + j];
    __syncthreads();

    float* ob = out + (size_t)b * Tt * Hh;
    const float* wbase = W + (size_t)j * Hh;

    float xp_cur = ob[j];
    int cur = 0;
    for (int t = 0; t < Tt; ++t) {
        float xp_next = (t + 1 < Tt) ? ob[(size_t)(t + 1) * Hh + j] : 0.0f;
        float4 a = make_float4(xp_cur, 0.0f, 0.0f, 0.0f);
        const float* h = hsb[cur];
        #pragma unroll 8
        for (int c4 = 0; c4 < Hh / 4; ++c4) {
            float4 wv = *reinterpret_cast<const float4*>(&wbase[c4 * 4]);
            float4 hv = *reinterpret_cast<const float4*>(&h[c4 * 4]);
            a.x += wv.x * hv.x; a.y += wv.y * hv.y;
            a.z += wv.z * hv.z; a.w += wv.w * hv.w;
        }
        float hn = tanhf((a.x + a.y) + (a.z + a.w));
        hsb[cur ^ 1][j] = hn;
        ob[(size_t)t * Hh + j] = hn;
        xp_cur = xp_next;
        cur ^= 1;
        __syncthreads();
    }
    out[(size_t)Bb * Tt * Hh + (size_t)b * Hh + j] = hsb[cur][j];
}

extern "C" void kernel_launch(void* const* d_in, const int* in_sizes, int n_in,
                              void* d_out, int out_size, void* d_ws, size_t ws_size,
                              hipStream_t stream)
{
    const float* x  = (const float*)d_in[0];
    const float* h0 = (const float*)d_in[1];
    const float* Wx = (const float*)d_in[2];
    const float* bx = (const float*)d_in[3];
    const float* Wh = (const float*)d_in[4];
    const float* bh = (const float*)d_in[5];
    float* out = (float*)d_out;

    dim3 g1(Bb * Tt / 128, Hh / 128);     // (512, 4)
    xproj_gemm<<<g1, 256, 0, stream>>>(x, Wx, bx, bh, out);

    const size_t flg_bytes = 512 * sizeof(unsigned int);
    const size_t xb_bytes  = (size_t)Bb * Hh * 2 * sizeof(float);
    if (ws_size >= flg_bytes + xb_bytes) {
        unsigned int* flags = (unsigned int*)d_ws;
        float* xbuf = (float*)((char*)d_ws + flg_bytes);
        zero_flags<<<1, 512, 0, stream>>>(flags);
        void* args[] = {(void*)&Wh, (void*)&h0, (void*)&out, (void*)&flags, (void*)&xbuf};
        hipLaunchCooperativeKernel((void*)rnn_scan_mb, dim3(NP * Bb), dim3(512),
                                   args, 0, stream);
    } else {
        rnn_scan_sb<<<Bb, Hh, 0, stream>>>(Wh, h0, out);
    }
}

// Round 7
// 3012.064 us; speedup vs baseline: 25.7610x; 1.5831x over previous
//
#include <hip/hip_runtime.h>

// VanillaRNNLayer: B=32, T=2048, I=512, H=512 — ALL FP32.
//   phase 1: xp = x @ Wx^T + bx + bh   -> fp32 into d_out (consumed in place)
//   phase 2: h_t = tanh(xp_t + Wh h_{t-1}), 8 blocks/chain, Wh slice in regs.
// R6 lesson: exchange was serialized flag-protocol (stage2 -> store -> vmcnt
// ack -> flag -> poll -> data load ~= 2000+ cy/step). R7: publish {tag,val}
// as ONE relaxed agent-scope u64 per row — no flags, no ack wait, no second
// hop; consumers poll the data itself. 2 barriers/step. Skew is structurally
// bounded to 1 step by the all-to-all dependence, so slot tags can't be
// overwritten early. xbuf zeroed per launch (tags monotonic per launch).

constexpr int Bb = 32, Tt = 2048, Ii = 512, Hh = 512;
constexpr int NP = 8;            // parts (blocks) per chain
constexpr int RP = Hh / NP;      // 64 rows per part

static __device__ __forceinline__ float fast_tanh(float x) {
    float ax = fabsf(x);
    float e = __expf(-2.0f * ax);            // in (0,1], no overflow
    float r = (1.0f - e) / (1.0f + e);
    return copysignf(r, x);
}

// ---------------- Phase 1: xp GEMM, 128x128 tile, 8x8/thread ----------------
// Measured ~0.34 ms ~= fp32 vector roofline for 34.4 GFLOP — done.
__global__ __launch_bounds__(256, 2)
void xproj_gemm(const float* __restrict__ x, const float* __restrict__ Wx,
                const float* __restrict__ bx, const float* __restrict__ bh,
                float* __restrict__ xp)
{
    constexpr int BM = 128, BK = 16, LDT = BM + 4;   // [k][m] transposed tiles
    __shared__ float As[BK][LDT];
    __shared__ float Bs[BK][LDT];

    const int tid = threadIdx.x;
    const int m0 = blockIdx.x * BM;
    const int n0 = blockIdx.y * BM;
    const int lrow = tid >> 1;               // 0..127
    const int lkh  = (tid & 1) * 8;          // 0 or 8
    const int tx = tid & 15, ty = tid >> 4;

    float acc[2][2][4][4] = {};

    for (int k0 = 0; k0 < Ii; k0 += BK) {
        float4 a0 = *reinterpret_cast<const float4*>(&x[(size_t)(m0 + lrow) * Ii + k0 + lkh]);
        float4 a1 = *reinterpret_cast<const float4*>(&x[(size_t)(m0 + lrow) * Ii + k0 + lkh + 4]);
        float4 b0 = *reinterpret_cast<const float4*>(&Wx[(size_t)(n0 + lrow) * Ii + k0 + lkh]);
        float4 b1 = *reinterpret_cast<const float4*>(&Wx[(size_t)(n0 + lrow) * Ii + k0 + lkh + 4]);
        __syncthreads();
        As[lkh + 0][lrow] = a0.x; As[lkh + 1][lrow] = a0.y;
        As[lkh + 2][lrow] = a0.z; As[lkh + 3][lrow] = a0.w;
        As[lkh + 4][lrow] = a1.x; As[lkh + 5][lrow] = a1.y;
        As[lkh + 6][lrow] = a1.z; As[lkh + 7][lrow] = a1.w;
        Bs[lkh + 0][lrow] = b0.x; Bs[lkh + 1][lrow] = b0.y;
        Bs[lkh + 2][lrow] = b0.z; Bs[lkh + 3][lrow] = b0.w;
        Bs[lkh + 4][lrow] = b1.x; Bs[lkh + 5][lrow] = b1.y;
        Bs[lkh + 6][lrow] = b1.z; Bs[lkh + 7][lrow] = b1.w;
        __syncthreads();
        #pragma unroll
        for (int k = 0; k < BK; ++k) {
            float4 av[2], bv[2];
            av[0] = *reinterpret_cast<const float4*>(&As[k][ty * 4]);
            av[1] = *reinterpret_cast<const float4*>(&As[k][64 + ty * 4]);
            bv[0] = *reinterpret_cast<const float4*>(&Bs[k][tx * 4]);
            bv[1] = *reinterpret_cast<const float4*>(&Bs[k][64 + tx * 4]);
            #pragma unroll
            for (int rh = 0; rh < 2; ++rh) {
                const float* ap = reinterpret_cast<const float*>(&av[rh]);
                #pragma unroll
                for (int ch = 0; ch < 2; ++ch) {
                    const float* bp = reinterpret_cast<const float*>(&bv[ch]);
                    #pragma unroll
                    for (int i = 0; i < 4; ++i)
                        #pragma unroll
                        for (int j = 0; j < 4; ++j)
                            acc[rh][ch][i][j] += ap[i] * bp[j];
                }
            }
        }
    }

    float4 bias[2];
    #pragma unroll
    for (int ch = 0; ch < 2; ++ch) {
        int cb = n0 + ch * 64 + tx * 4;
        bias[ch] = make_float4(bx[cb] + bh[cb], bx[cb + 1] + bh[cb + 1],
                               bx[cb + 2] + bh[cb + 2], bx[cb + 3] + bh[cb + 3]);
    }
    #pragma unroll
    for (int rh = 0; rh < 2; ++rh)
        #pragma unroll
        for (int i = 0; i < 4; ++i) {
            size_t row = (size_t)(m0 + rh * 64 + ty * 4 + i);
            #pragma unroll
            for (int ch = 0; ch < 2; ++ch) {
                const float* bp = reinterpret_cast<const float*>(&bias[ch]);
                float4 v = make_float4(acc[rh][ch][i][0] + bp[0], acc[rh][ch][i][1] + bp[1],
                                       acc[rh][ch][i][2] + bp[2], acc[rh][ch][i][3] + bp[3]);
                *reinterpret_cast<float4*>(&xp[row * Hh + n0 + ch * 64 + tx * 4]) = v;
            }
        }
}

// ---------------- zero xbuf (every launch: tags are per-launch monotonic) ----
__global__ void zero_xbuf(unsigned long long* __restrict__ xb)
{
    xb[(size_t)blockIdx.x * 512 + threadIdx.x] = 0ull;   // 64 blocks x 512
}

// ---------------- Phase 2: scan, 8 blocks/chain, one-qword exchange ---------
// bid: chain c = bid&31, part P = bid>>5. Wave w (0..7), lane (hf,lp):
// thread rows P*64 + w*8 + hf*4 + s (s=0..3), cols q*128 + lp*4 + i.
// Wave P = finisher (tanh+publish for rows P*64+lane); waves w!=P poll
// part w's qwords {tag,val} directly. 2 barriers/step.
__global__ __launch_bounds__(512, 1)
void rnn_scan_mb(const float* __restrict__ Wh, const float* __restrict__ h0,
                 float* __restrict__ out, unsigned long long* __restrict__ xbuf)
{
    const int bid = blockIdx.x;
    const int c = bid & 31;
    const int P = bid >> 5;
    const int tid = threadIdx.x;
    const int w = tid >> 6;          // wave 0..7
    const int lane = tid & 63;
    const int hf = lane >> 5, lp = lane & 31;
    const int lrow0 = w * 8 + hf * 4;          // local row base 0..60

    __shared__ __align__(16) float hs[Hh];
    __shared__ __align__(16) float pacc[RP][36];   // [local row][lp], b128-aligned

    // ---- weights -> registers via opaque asm loads (no remat possible) ----
    float4 wreg[4][4];
    #pragma unroll
    for (int s = 0; s < 4; ++s)
        #pragma unroll
        for (int q = 0; q < 4; ++q) {
            const float* ap = &Wh[(size_t)(P * RP + lrow0 + s) * Hh + q * 128 + lp * 4];
            asm volatile("global_load_dwordx4 %0, %1, off"
                         : "=v"(wreg[s][q]) : "v"(ap));
        }
    asm volatile("s_waitcnt vmcnt(0)" ::: "memory");

    hs[tid] = h0[(size_t)c * Hh + tid];

    float* ob = out + (size_t)c * Tt * Hh;            // xp rows -> h rows in place
    unsigned long long* xb = xbuf + (size_t)c * 2 * Hh;   // [slot][row]

    float xp_cur = 0.f;
    if (w == P) xp_cur = ob[P * RP + lane];           // finisher: xp row t=0
    __syncthreads();                                  // hs = h0 ready

    for (int t = 0; t < Tt; ++t) {
        // ---- FMA: 4 rows x 16 interleaved cols per thread
        float4 hv[4];
        #pragma unroll
        for (int q = 0; q < 4; ++q)
            hv[q] = *reinterpret_cast<const float4*>(&hs[q * 128 + lp * 4]);
        #pragma unroll
        for (int s = 0; s < 4; ++s) {
            float sum = 0.f;
            #pragma unroll
            for (int q = 0; q < 4; ++q) {
                const float* wq = reinterpret_cast<const float*>(&wreg[s][q]);
                const float* hq = reinterpret_cast<const float*>(&hv[q]);
                sum += wq[0] * hq[0]; sum += wq[1] * hq[1];
                sum += wq[2] * hq[2]; sum += wq[3] * hq[3];
            }
            pacc[lrow0 + s][lp] = sum;
        }
        __syncthreads();                 // B-mid: pacc ready; hs reads done

        if (w == P) {
            // ---- finisher: row = P*64 + lane
            float ssum = xp_cur;
            #pragma unroll
            for (int q = 0; q < 8; ++q) {
                float4 p4 = *reinterpret_cast<const float4*>(&pacc[lane][q * 4]);
                ssum += (p4.x + p4.y) + (p4.z + p4.w);
            }
            float hval = fast_tanh(ssum);
            ob[(size_t)t * Hh + P * RP + lane] = hval;
            if (t + 1 < Tt) {
                unsigned long long msg =
                    ((unsigned long long)(unsigned)(t + 1) << 32) |
                    (unsigned long long)__float_as_uint(hval);
                __hip_atomic_store(&xb[(size_t)(t & 1) * Hh + P * RP + lane], msg,
                                   __ATOMIC_RELAXED, __HIP_MEMORY_SCOPE_AGENT);
                hs[P * RP + lane] = hval;
                xp_cur = ob[(size_t)(t + 1) * Hh + P * RP + lane];   // prefetch
            } else {
                out[(size_t)Bb * Tt * Hh + (size_t)c * Hh + P * RP + lane] = hval;
            }
        } else if (t + 1 < Tt) {
            // ---- fetch: wave w polls part w's qwords (data IS the flag)
            const unsigned want = (unsigned)(t + 1);
            unsigned long long msg;
            do {
                msg = __hip_atomic_load(&xb[(size_t)(t & 1) * Hh + w * RP + lane],
                                        __ATOMIC_RELAXED, __HIP_MEMORY_SCOPE_AGENT);
            } while ((unsigned)(msg >> 32) != want);
            hs[w * RP + lane] = __uint_as_float((unsigned)msg);
        }
        __syncthreads();                 // B-end: hs = h(t) ready
    }
}

// ---------------- Fallback single-block scan (tiny ws) ----------------
__global__ __launch_bounds__(512)
void rnn_scan_sb(const float* __restrict__ W, const float* __restrict__ h0,
                 float* __restrict__ out)
{
    const int b = blockIdx.x;
    const int j = threadIdx.x;
    __shared__ float hsb[2][Hh];
    hsb[0][j] = h0[(size_t)b * Hh + j];
    __syncthreads();

    float* ob = out + (size_t)b * Tt * Hh;
    const float* wbase = W + (size_t)j * Hh;

    float xp_cur = ob[j];
    int cur = 0;
    for (int t = 0; t < Tt; ++t) {
        float xp_next = (t + 1 < Tt) ? ob[(size_t)(t + 1) * Hh + j] : 0.0f;
        float4 a = make_float4(xp_cur, 0.0f, 0.0f, 0.0f);
        const float* h = hsb[cur];
        #pragma unroll 8
        for (int c4 = 0; c4 < Hh / 4; ++c4) {
            float4 wv = *reinterpret_cast<const float4*>(&wbase[c4 * 4]);
            float4 hv = *reinterpret_cast<const float4*>(&h[c4 * 4]);
            a.x += wv.x * hv.x; a.y += wv.y * hv.y;
            a.z += wv.z * hv.z; a.w += wv.w * hv.w;
        }
        float hn = tanhf((a.x + a.y) + (a.z + a.w));
        hsb[cur ^ 1][j] = hn;
        ob[(size_t)t * Hh + j] = hn;
        xp_cur = xp_next;
        cur ^= 1;
        __syncthreads();
    }
    out[(size_t)Bb * Tt * Hh + (size_t)b * Hh + j] = hsb[cur][j];
}

extern "C" void kernel_launch(void* const* d_in, const int* in_sizes, int n_in,
                              void* d_out, int out_size, void* d_ws, size_t ws_size,
                              hipStream_t stream)
{
    const float* x  = (const float*)d_in[0];
    const float* h0 = (const float*)d_in[1];
    const float* Wx = (const float*)d_in[2];
    const float* bx = (const float*)d_in[3];
    const float* Wh = (const float*)d_in[4];
    const float* bh = (const float*)d_in[5];
    float* out = (float*)d_out;

    dim3 g1(Bb * Tt / 128, Hh / 128);     // (512, 4)
    xproj_gemm<<<g1, 256, 0, stream>>>(x, Wx, bx, bh, out);

    const size_t xb_bytes = (size_t)Bb * 2 * Hh * sizeof(unsigned long long); // 256 KB
    if (ws_size >= xb_bytes) {
        unsigned long long* xbuf = (unsigned long long*)d_ws;
        zero_xbuf<<<64, 512, 0, stream>>>(xbuf);
        void* args[] = {(void*)&Wh, (void*)&h0, (void*)&out, (void*)&xbuf};
        hipLaunchCooperativeKernel((void*)rnn_scan_mb, dim3(NP * Bb), dim3(512),
                                   args, 0, stream);
    } else {
        rnn_scan_sb<<<Bb, Hh, 0, stream>>>(Wh, h0, out);
    }
}